// Round 1
// baseline (881.146 us; speedup 1.0000x reference)
//
#include <hip/hip_runtime.h>

// Problem constants
#define S_LEN 2048
#define B_SZ  2
#define F_DIM 1024
#define H_N   16
#define D_DIM 64
#define P_DIM 1024           // H*D
#define M_ROWS 4096          // S*B
#define NBH   32             // B*H

typedef __bf16 bf16x8 __attribute__((ext_vector_type(8)));
typedef float  f32x4  __attribute__((ext_vector_type(4)));
typedef unsigned short u16;
typedef unsigned short u16x8 __attribute__((ext_vector_type(8)));
typedef unsigned short u16x4 __attribute__((ext_vector_type(4)));

__device__ __forceinline__ float bf2f(u16 u) {
  union { unsigned int i; float f; } x;
  x.i = ((unsigned int)u) << 16;
  return x.f;
}
__device__ __forceinline__ u16 f2bf(float f) {
  union { float f; unsigned int i; } x;
  x.f = f;
  unsigned int u = x.i;
  u += 0x7fffu + ((u >> 16) & 1u);   // round-to-nearest-even
  return (u16)(u >> 16);
}

// ---------------- f32 -> bf16 convert (vectorized) ----------------
__global__ __launch_bounds__(256) void cvt_f32_bf16(const float* __restrict__ in,
                                                    u16* __restrict__ out, int n4) {
  int i = blockIdx.x * 256 + threadIdx.x;
  if (i >= n4) return;
  f32x4 v = *reinterpret_cast<const f32x4*>(in + (size_t)i * 4);
  u16x4 o;
  o[0] = f2bf(v[0]); o[1] = f2bf(v[1]); o[2] = f2bf(v[2]); o[3] = f2bf(v[3]);
  *reinterpret_cast<u16x4*>(out + (size_t)i * 4) = o;
}

// ---------------- QKV projection GEMM ----------------
// C[m][p] = sum_f A[m][f] * W[p][f] + bias[p];  A: [4096][1024] bf16, W: [3072][1024] bf16
// Epilogue: scale q by 0.125, scatter to q_ws [n][s][d], kt_ws [n][d][s], v_ws [n][s][d] (bf16)
// Block: 128(M) x 64(N), 4 waves; wave owns 32 rows (2 A-frag stripes) x 64 cols (4 n-subtiles).
__global__ __launch_bounds__(256) void qkv_gemm(const u16* __restrict__ A,
                                                const u16* __restrict__ W,
                                                const float* __restrict__ bias,
                                                u16* __restrict__ qw,
                                                u16* __restrict__ ktw,
                                                u16* __restrict__ vw) {
  const int lane = threadIdx.x & 63;
  const int wave = threadIdx.x >> 6;
  const int bm = blockIdx.y * 128;
  const int bn = blockIdx.x * 64;
  const int fr = lane & 15;            // fragment row (m or n within 16)
  const int koff = (lane >> 4) * 8;    // k offset within 32-step

  const u16* Ap0 = A + (size_t)(bm + wave * 32 + fr) * 1024;
  const u16* Ap1 = Ap0 + 16 * 1024;
  const u16* Wp  = W + (size_t)(bn + fr) * 1024;

  f32x4 acc[2][4];
  #pragma unroll
  for (int ai = 0; ai < 2; ai++)
    #pragma unroll
    for (int nt = 0; nt < 4; nt++) {
      f32x4 z = {0.f, 0.f, 0.f, 0.f};
      acc[ai][nt] = z;
    }

  for (int k0 = 0; k0 < 1024; k0 += 32) {
    const int k = k0 + koff;
    bf16x8 a0 = *reinterpret_cast<const bf16x8*>(Ap0 + k);
    bf16x8 a1 = *reinterpret_cast<const bf16x8*>(Ap1 + k);
    #pragma unroll
    for (int nt = 0; nt < 4; nt++) {
      bf16x8 b = *reinterpret_cast<const bf16x8*>(Wp + (size_t)nt * 16 * 1024 + k);
      acc[0][nt] = __builtin_amdgcn_mfma_f32_16x16x32_bf16(a0, b, acc[0][nt], 0, 0, 0);
      acc[1][nt] = __builtin_amdgcn_mfma_f32_16x16x32_bf16(a1, b, acc[1][nt], 0, 0, 0);
    }
  }

  // C/D layout: col = lane&15, row = (lane>>4)*4 + reg   [verified mapping]
  #pragma unroll
  for (int ai = 0; ai < 2; ai++) {
    #pragma unroll
    for (int nt = 0; nt < 4; nt++) {
      const int p = bn + nt * 16 + (lane & 15);
      const float bv = bias[p];
      const int which = p >> 10;          // 0=q 1=k 2=v
      const int pp = p & 1023;
      const int h = pp >> 6, d = pp & 63;
      const float scale = (which == 0) ? 0.125f : 1.0f;
      #pragma unroll
      for (int r = 0; r < 4; r++) {
        const int m = bm + wave * 32 + ai * 16 + (lane >> 4) * 4 + r;
        const int s = m >> 1, b_ = m & 1;
        const int n = b_ * 16 + h;
        const float v = (acc[ai][nt][r] + bv) * scale;
        const u16 hv = f2bf(v);
        if (which == 0)      qw [((size_t)n * 2048 + s) * 64 + d] = hv;
        else if (which == 1) ktw[((size_t)n * 64 + d) * 2048 + s] = hv;
        else                 vw [((size_t)n * 2048 + s) * 64 + d] = hv;
      }
    }
  }
}

// ---------------- Output projection GEMM ----------------
// out[m][f] = sum_p A[m][p] * W[f][p] + bias[f];  fp32 output
__global__ __launch_bounds__(256) void out_gemm(const u16* __restrict__ A,
                                                const u16* __restrict__ W,
                                                const float* __restrict__ bias,
                                                float* __restrict__ out) {
  const int lane = threadIdx.x & 63;
  const int wave = threadIdx.x >> 6;
  const int bm = blockIdx.y * 128;
  const int bn = blockIdx.x * 64;
  const int fr = lane & 15;
  const int koff = (lane >> 4) * 8;

  const u16* Ap0 = A + (size_t)(bm + wave * 32 + fr) * 1024;
  const u16* Ap1 = Ap0 + 16 * 1024;
  const u16* Wp  = W + (size_t)(bn + fr) * 1024;

  f32x4 acc[2][4];
  #pragma unroll
  for (int ai = 0; ai < 2; ai++)
    #pragma unroll
    for (int nt = 0; nt < 4; nt++) {
      f32x4 z = {0.f, 0.f, 0.f, 0.f};
      acc[ai][nt] = z;
    }

  for (int k0 = 0; k0 < 1024; k0 += 32) {
    const int k = k0 + koff;
    bf16x8 a0 = *reinterpret_cast<const bf16x8*>(Ap0 + k);
    bf16x8 a1 = *reinterpret_cast<const bf16x8*>(Ap1 + k);
    #pragma unroll
    for (int nt = 0; nt < 4; nt++) {
      bf16x8 b = *reinterpret_cast<const bf16x8*>(Wp + (size_t)nt * 16 * 1024 + k);
      acc[0][nt] = __builtin_amdgcn_mfma_f32_16x16x32_bf16(a0, b, acc[0][nt], 0, 0, 0);
      acc[1][nt] = __builtin_amdgcn_mfma_f32_16x16x32_bf16(a1, b, acc[1][nt], 0, 0, 0);
    }
  }

  #pragma unroll
  for (int ai = 0; ai < 2; ai++) {
    #pragma unroll
    for (int nt = 0; nt < 4; nt++) {
      const int f = bn + nt * 16 + (lane & 15);
      const float bv = bias[f];
      #pragma unroll
      for (int r = 0; r < 4; r++) {
        const int m = bm + wave * 32 + ai * 16 + (lane >> 4) * 4 + r;
        out[(size_t)m * 1024 + f] = acc[ai][nt][r] + bv;
      }
    }
  }
}

// ---------------- Flash attention (fp32 vector), 64x64 tiles ----------------
// grid: (32 q-tiles, 32 head-batches), 256 threads.
// thread (tr=tid/16, tc=tid%16) owns rows r0=4*tr..+4, cols c0=4*tc..+4.
__global__ __launch_bounds__(256) void attn_fwd(const u16* __restrict__ qw,
                                                const u16* __restrict__ ktw,
                                                const u16* __restrict__ vw,
                                                u16* __restrict__ ao) {
  __shared__ float Qs[64][64];   // [q-row][d]
  __shared__ float Ks[64][64];   // [d][key]   (K transposed)
  __shared__ float Vs[64][64];   // [key][d]
  __shared__ float Ps[64][64];   // [q-row][key]

  const int tid = threadIdx.x;
  const int n = blockIdx.y;              // head-batch: n = b*16 + h
  const int qs0 = blockIdx.x * 64;
  const int b_ = n >> 4, h = n & 15;

  const int tr = tid >> 4;
  const int tc = tid & 15;
  const int r0 = tr * 4, c0 = tc * 4;

  // load Q tile (64x64): 512 chunks of 8 bf16
  {
    const u16* qbase = qw + ((size_t)n * 2048 + qs0) * 64;
    #pragma unroll
    for (int it = 0; it < 2; it++) {
      const int chunk = tid + it * 256;
      const int row = chunk >> 3, c8 = (chunk & 7) * 8;
      u16x8 v = *reinterpret_cast<const u16x8*>(qbase + (size_t)row * 64 + c8);
      f32x4 lo, hi;
      lo[0]=bf2f(v[0]); lo[1]=bf2f(v[1]); lo[2]=bf2f(v[2]); lo[3]=bf2f(v[3]);
      hi[0]=bf2f(v[4]); hi[1]=bf2f(v[5]); hi[2]=bf2f(v[6]); hi[3]=bf2f(v[7]);
      *reinterpret_cast<f32x4*>(&Qs[row][c8])     = lo;
      *reinterpret_cast<f32x4*>(&Qs[row][c8 + 4]) = hi;
    }
  }

  f32x4 O4[4];
  float m_run[4], l_run[4];
  #pragma unroll
  for (int i = 0; i < 4; i++) {
    f32x4 z = {0.f, 0.f, 0.f, 0.f};
    O4[i] = z;
    m_run[i] = -1e30f;
    l_run[i] = 0.f;
  }

  for (int kt = 0; kt < 32; kt++) {
    __syncthreads();  // prev PV done (and Q visible on first iter)
    const int ks0 = kt * 64;
    {
      const u16* kbase = ktw + (size_t)n * 64 * 2048 + ks0;
      const u16* vbase = vw + ((size_t)n * 2048 + ks0) * 64;
      #pragma unroll
      for (int it = 0; it < 2; it++) {
        const int chunk = tid + it * 256;
        const int row = chunk >> 3, c8 = (chunk & 7) * 8;
        u16x8 kv = *reinterpret_cast<const u16x8*>(kbase + (size_t)row * 2048 + c8);
        u16x8 vv = *reinterpret_cast<const u16x8*>(vbase + (size_t)row * 64 + c8);
        f32x4 lo, hi;
        lo[0]=bf2f(kv[0]); lo[1]=bf2f(kv[1]); lo[2]=bf2f(kv[2]); lo[3]=bf2f(kv[3]);
        hi[0]=bf2f(kv[4]); hi[1]=bf2f(kv[5]); hi[2]=bf2f(kv[6]); hi[3]=bf2f(kv[7]);
        *reinterpret_cast<f32x4*>(&Ks[row][c8])     = lo;
        *reinterpret_cast<f32x4*>(&Ks[row][c8 + 4]) = hi;
        lo[0]=bf2f(vv[0]); lo[1]=bf2f(vv[1]); lo[2]=bf2f(vv[2]); lo[3]=bf2f(vv[3]);
        hi[0]=bf2f(vv[4]); hi[1]=bf2f(vv[5]); hi[2]=bf2f(vv[6]); hi[3]=bf2f(vv[7]);
        *reinterpret_cast<f32x4*>(&Vs[row][c8])     = lo;
        *reinterpret_cast<f32x4*>(&Vs[row][c8 + 4]) = hi;
      }
    }
    __syncthreads();  // tiles ready

    // S = Q K^T for this tile: s4[i][j] = score(row r0+i, key c0+j)
    f32x4 s4[4];
    #pragma unroll
    for (int i = 0; i < 4; i++) { f32x4 z = {0.f,0.f,0.f,0.f}; s4[i] = z; }
    #pragma unroll
    for (int k = 0; k < 64; k += 4) {
      f32x4 qv[4], kv[4];
      #pragma unroll
      for (int i = 0; i < 4; i++) qv[i] = *reinterpret_cast<const f32x4*>(&Qs[r0 + i][k]);
      #pragma unroll
      for (int kk = 0; kk < 4; kk++) kv[kk] = *reinterpret_cast<const f32x4*>(&Ks[k + kk][c0]);
      #pragma unroll
      for (int i = 0; i < 4; i++) {
        #pragma unroll
        for (int kk = 0; kk < 4; kk++) s4[i] += kv[kk] * qv[i][kk];
      }
    }

    // online softmax (row groups = 16 consecutive lanes, same tr)
    #pragma unroll
    for (int i = 0; i < 4; i++) {
      float rm = fmaxf(fmaxf(s4[i][0], s4[i][1]), fmaxf(s4[i][2], s4[i][3]));
      rm = fmaxf(rm, __shfl_xor(rm, 1));
      rm = fmaxf(rm, __shfl_xor(rm, 2));
      rm = fmaxf(rm, __shfl_xor(rm, 4));
      rm = fmaxf(rm, __shfl_xor(rm, 8));
      const float mnew = fmaxf(m_run[i], rm);
      const float corr = __expf(m_run[i] - mnew);
      f32x4 p;
      #pragma unroll
      for (int j = 0; j < 4; j++) p[j] = __expf(s4[i][j] - mnew);
      float rs = p[0] + p[1] + p[2] + p[3];
      rs += __shfl_xor(rs, 1);
      rs += __shfl_xor(rs, 2);
      rs += __shfl_xor(rs, 4);
      rs += __shfl_xor(rs, 8);
      l_run[i] = l_run[i] * corr + rs;
      m_run[i] = mnew;
      O4[i] *= corr;
      *reinterpret_cast<f32x4*>(&Ps[r0 + i][c0]) = p;
    }
    __syncthreads();  // P ready

    // O += P V
    #pragma unroll
    for (int k = 0; k < 64; k += 4) {
      f32x4 pp[4], vv[4];
      #pragma unroll
      for (int i = 0; i < 4; i++) pp[i] = *reinterpret_cast<const f32x4*>(&Ps[r0 + i][k]);
      #pragma unroll
      for (int kk = 0; kk < 4; kk++) vv[kk] = *reinterpret_cast<const f32x4*>(&Vs[k + kk][c0]);
      #pragma unroll
      for (int i = 0; i < 4; i++) {
        #pragma unroll
        for (int kk = 0; kk < 4; kk++) O4[i] += vv[kk] * pp[i][kk];
      }
    }
  }

  // epilogue: O/l -> attn_out bf16 [m=s*2+b][p=h*64+d]
  #pragma unroll
  for (int i = 0; i < 4; i++) {
    const float inv = 1.0f / l_run[i];
    u16x4 o;
    o[0] = f2bf(O4[i][0] * inv);
    o[1] = f2bf(O4[i][1] * inv);
    o[2] = f2bf(O4[i][2] * inv);
    o[3] = f2bf(O4[i][3] * inv);
    const size_t m = (size_t)(qs0 + r0 + i) * 2 + b_;
    *reinterpret_cast<u16x4*>(ao + m * 1024 + h * 64 + c0) = o;
  }
}

// ---------------- launch ----------------
extern "C" void kernel_launch(void* const* d_in, const int* in_sizes, int n_in,
                              void* d_out, int out_size, void* d_ws, size_t ws_size,
                              hipStream_t stream) {
  const float* src   = (const float*)d_in[0];
  const float* w_in  = (const float*)d_in[1];
  const float* b_in  = (const float*)d_in[2];
  const float* w_out = (const float*)d_in[3];
  const float* b_out = (const float*)d_in[4];
  float* out = (float*)d_out;

  char* ws = (char*)d_ws;
  u16* srcb = (u16*)(ws);                         //  8 MB  src bf16 [4096][1024]
  u16* wib  = (u16*)(ws + ((size_t)8  << 20));    //  6 MB  W_in bf16 [3072][1024]
  u16* wob  = (u16*)(ws + ((size_t)14 << 20));    //  2 MB  W_out bf16 [1024][1024]
  u16* qw   = (u16*)(ws + ((size_t)16 << 20));    //  8 MB  q bf16 [32][2048][64]
  u16* ktw  = (u16*)(ws + ((size_t)24 << 20));    //  8 MB  k^T bf16 [32][64][2048]
  u16* vw   = (u16*)(ws + ((size_t)32 << 20));    //  8 MB  v bf16 [32][2048][64]
  u16* ao   = (u16*)(ws + ((size_t)40 << 20));    //  8 MB  attn out bf16 [4096][1024]

  cvt_f32_bf16<<<4096, 256, 0, stream>>>(src,   srcb, 4096 * 1024 / 4);
  cvt_f32_bf16<<<3072, 256, 0, stream>>>(w_in,  wib,  3072 * 1024 / 4);
  cvt_f32_bf16<<<1024, 256, 0, stream>>>(w_out, wob,  1024 * 1024 / 4);

  qkv_gemm<<<dim3(48, 32), 256, 0, stream>>>(srcb, wib, b_in, qw, ktw, vw);
  attn_fwd<<<dim3(32, 32), 256, 0, stream>>>(qw, ktw, vw, ao);
  out_gemm<<<dim3(16, 32), 256, 0, stream>>>(ao, wob, b_out, out);
}

// Round 2
// 427.969 us; speedup vs baseline: 2.0589x; 2.0589x over previous
//
#include <hip/hip_runtime.h>

// Problem constants
#define S_LEN 2048
#define B_SZ  2
#define F_DIM 1024
#define H_N   16
#define D_DIM 64
#define P_DIM 1024           // H*D
#define M_ROWS 4096          // S*B
#define NBH   32             // B*H

typedef __bf16 bf16x8 __attribute__((ext_vector_type(8)));
typedef float  f32x4  __attribute__((ext_vector_type(4)));
typedef unsigned short u16;
typedef unsigned short u16x8 __attribute__((ext_vector_type(8)));
typedef unsigned short u16x4 __attribute__((ext_vector_type(4)));

__device__ __forceinline__ float bf2f(u16 u) {
  union { unsigned int i; float f; } x;
  x.i = ((unsigned int)u) << 16;
  return x.f;
}
__device__ __forceinline__ u16 f2bf(float f) {
  union { float f; unsigned int i; } x;
  x.f = f;
  unsigned int u = x.i;
  u += 0x7fffu + ((u >> 16) & 1u);   // round-to-nearest-even
  return (u16)(u >> 16);
}

// ---------------- f32 -> bf16 convert (vectorized) ----------------
__global__ __launch_bounds__(256) void cvt_f32_bf16(const float* __restrict__ in,
                                                    u16* __restrict__ out, int n4) {
  int i = blockIdx.x * 256 + threadIdx.x;
  if (i >= n4) return;
  f32x4 v = *reinterpret_cast<const f32x4*>(in + (size_t)i * 4);
  u16x4 o;
  o[0] = f2bf(v[0]); o[1] = f2bf(v[1]); o[2] = f2bf(v[2]); o[3] = f2bf(v[3]);
  *reinterpret_cast<u16x4*>(out + (size_t)i * 4) = o;
}

// ---------------- QKV projection GEMM ----------------
// C[m][p] = sum_f A[m][f] * W[p][f] + bias[p];  A: [4096][1024] bf16, W: [3072][1024] bf16
// Epilogue: scale q by 0.125; scatter to
//   qw [n][s][d]  (scaled q)
//   kw [n][s][d]  (k, row-major — MFMA B-frag wants K rows)
//   vt [n][d][s]  (v transposed — MFMA B-frag for PV wants V^T rows)
__global__ __launch_bounds__(256) void qkv_gemm(const u16* __restrict__ A,
                                                const u16* __restrict__ W,
                                                const float* __restrict__ bias,
                                                u16* __restrict__ qw,
                                                u16* __restrict__ kw,
                                                u16* __restrict__ vt) {
  const int lane = threadIdx.x & 63;
  const int wave = threadIdx.x >> 6;
  const int bm = blockIdx.y * 128;
  const int bn = blockIdx.x * 64;
  const int fr = lane & 15;            // fragment row (m or n within 16)
  const int koff = (lane >> 4) * 8;    // k offset within 32-step

  const u16* Ap0 = A + (size_t)(bm + wave * 32 + fr) * 1024;
  const u16* Ap1 = Ap0 + 16 * 1024;
  const u16* Wp  = W + (size_t)(bn + fr) * 1024;

  f32x4 acc[2][4];
  #pragma unroll
  for (int ai = 0; ai < 2; ai++)
    #pragma unroll
    for (int nt = 0; nt < 4; nt++) {
      f32x4 z = {0.f, 0.f, 0.f, 0.f};
      acc[ai][nt] = z;
    }

  for (int k0 = 0; k0 < 1024; k0 += 32) {
    const int k = k0 + koff;
    bf16x8 a0 = *reinterpret_cast<const bf16x8*>(Ap0 + k);
    bf16x8 a1 = *reinterpret_cast<const bf16x8*>(Ap1 + k);
    #pragma unroll
    for (int nt = 0; nt < 4; nt++) {
      bf16x8 b = *reinterpret_cast<const bf16x8*>(Wp + (size_t)nt * 16 * 1024 + k);
      acc[0][nt] = __builtin_amdgcn_mfma_f32_16x16x32_bf16(a0, b, acc[0][nt], 0, 0, 0);
      acc[1][nt] = __builtin_amdgcn_mfma_f32_16x16x32_bf16(a1, b, acc[1][nt], 0, 0, 0);
    }
  }

  // C/D layout: col = lane&15, row = (lane>>4)*4 + reg   [verified mapping]
  #pragma unroll
  for (int ai = 0; ai < 2; ai++) {
    #pragma unroll
    for (int nt = 0; nt < 4; nt++) {
      const int p = bn + nt * 16 + (lane & 15);
      const float bv = bias[p];
      const int which = p >> 10;          // 0=q 1=k 2=v
      const int pp = p & 1023;
      const int h = pp >> 6, d = pp & 63;
      const float scale = (which == 0) ? 0.125f : 1.0f;
      #pragma unroll
      for (int r = 0; r < 4; r++) {
        const int m = bm + wave * 32 + ai * 16 + (lane >> 4) * 4 + r;
        const int s = m >> 1, b_ = m & 1;
        const int n = b_ * 16 + h;
        const float v = (acc[ai][nt][r] + bv) * scale;
        const u16 hv = f2bf(v);
        if (which == 0)      qw[((size_t)n * 2048 + s) * 64 + d] = hv;
        else if (which == 1) kw[((size_t)n * 2048 + s) * 64 + d] = hv;
        else                 vt[((size_t)n * 64 + d) * 2048 + s] = hv;
      }
    }
  }
}

// ---------------- Output projection GEMM ----------------
// out[m][f] = sum_p A[m][p] * W[f][p] + bias[f];  fp32 output
__global__ __launch_bounds__(256) void out_gemm(const u16* __restrict__ A,
                                                const u16* __restrict__ W,
                                                const float* __restrict__ bias,
                                                float* __restrict__ out) {
  const int lane = threadIdx.x & 63;
  const int wave = threadIdx.x >> 6;
  const int bm = blockIdx.y * 128;
  const int bn = blockIdx.x * 64;
  const int fr = lane & 15;
  const int koff = (lane >> 4) * 8;

  const u16* Ap0 = A + (size_t)(bm + wave * 32 + fr) * 1024;
  const u16* Ap1 = Ap0 + 16 * 1024;
  const u16* Wp  = W + (size_t)(bn + fr) * 1024;

  f32x4 acc[2][4];
  #pragma unroll
  for (int ai = 0; ai < 2; ai++)
    #pragma unroll
    for (int nt = 0; nt < 4; nt++) {
      f32x4 z = {0.f, 0.f, 0.f, 0.f};
      acc[ai][nt] = z;
    }

  for (int k0 = 0; k0 < 1024; k0 += 32) {
    const int k = k0 + koff;
    bf16x8 a0 = *reinterpret_cast<const bf16x8*>(Ap0 + k);
    bf16x8 a1 = *reinterpret_cast<const bf16x8*>(Ap1 + k);
    #pragma unroll
    for (int nt = 0; nt < 4; nt++) {
      bf16x8 b = *reinterpret_cast<const bf16x8*>(Wp + (size_t)nt * 16 * 1024 + k);
      acc[0][nt] = __builtin_amdgcn_mfma_f32_16x16x32_bf16(a0, b, acc[0][nt], 0, 0, 0);
      acc[1][nt] = __builtin_amdgcn_mfma_f32_16x16x32_bf16(a1, b, acc[1][nt], 0, 0, 0);
    }
  }

  #pragma unroll
  for (int ai = 0; ai < 2; ai++) {
    #pragma unroll
    for (int nt = 0; nt < 4; nt++) {
      const int f = bn + nt * 16 + (lane & 15);
      const float bv = bias[f];
      #pragma unroll
      for (int r = 0; r < 4; r++) {
        const int m = bm + wave * 32 + ai * 16 + (lane >> 4) * 4 + r;
        out[(size_t)m * 1024 + f] = acc[ai][nt][r] + bv;
      }
    }
  }
}

// ---------------- Flash attention, bf16 MFMA ----------------
// grid: (32 q-tiles, 32 head-batches), 256 threads = 4 waves.
// Each wave owns 16 q-rows; iterates 32 KV tiles of 64 keys.
// QK^T: A=Q rows (regs), B=K rows (global, L2-resident). S in C-layout.
// Softmax: in-lane over 4 key-subtiles + __shfl_xor over 16 key-lanes.
// P: C-layout -> A-layout via per-wave LDS [16][72] bf16 (padded; no barriers).
// PV: A=P (LDS), B=V^T rows (global).
__global__ __launch_bounds__(256) void attn_fwd(const u16* __restrict__ qw,
                                                const u16* __restrict__ kw,
                                                const u16* __restrict__ vt,
                                                u16* __restrict__ ao) {
  __shared__ u16 Pl[4][16][72];   // per-wave P buffer, +8 pad => conflict-even b128 reads

  const int tid = threadIdx.x;
  const int wave = tid >> 6;
  const int lane = tid & 63;
  const int c = lane & 15;        // frag row/col index
  const int g = lane >> 4;        // k-group within frag
  const int n = blockIdx.y;       // head-batch: n = b*16 + h
  const int qs0 = blockIdx.x * 64;
  const int b_ = n >> 4, h = n & 15;
  const int q0 = qs0 + wave * 16;

  // Q A-frags (held in registers for all 32 KV tiles); q pre-scaled by 1/8
  const u16* qp = qw + ((size_t)n * 2048 + q0 + c) * 64 + g * 8;
  const bf16x8 qa0 = *reinterpret_cast<const bf16x8*>(qp);
  const bf16x8 qa1 = *reinterpret_cast<const bf16x8*>(qp + 32);

  const u16* kbase = kw + (size_t)n * 2048 * 64;   // [s][d]
  const u16* vbase = vt + (size_t)n * 64 * 2048;   // [d][s]

  f32x4 O[4];                     // [dt], rows r=0..3 in regs
  float m_run[4], l_run[4];
  #pragma unroll
  for (int i = 0; i < 4; i++) {
    f32x4 z = {0.f, 0.f, 0.f, 0.f};
    O[i] = z;
    m_run[i] = -1e30f;
    l_run[i] = 0.f;
  }

  for (int kt = 0; kt < 32; kt++) {
    const int ks0 = kt * 64;

    // ---- S = Q K^T (16 q x 64 keys): 4 key-subtiles x 2 k-steps ----
    f32x4 s4[4];
    #pragma unroll
    for (int st = 0; st < 4; st++) { f32x4 z = {0.f,0.f,0.f,0.f}; s4[st] = z; }
    #pragma unroll
    for (int st = 0; st < 4; st++) {
      const u16* kp = kbase + (size_t)(ks0 + st * 16 + c) * 64 + g * 8;
      bf16x8 kb0 = *reinterpret_cast<const bf16x8*>(kp);
      bf16x8 kb1 = *reinterpret_cast<const bf16x8*>(kp + 32);
      s4[st] = __builtin_amdgcn_mfma_f32_16x16x32_bf16(qa0, kb0, s4[st], 0, 0, 0);
      s4[st] = __builtin_amdgcn_mfma_f32_16x16x32_bf16(qa1, kb1, s4[st], 0, 0, 0);
    }

    // ---- online softmax; rows q_local = g*4 + r ----
    #pragma unroll
    for (int r = 0; r < 4; r++) {
      float rm = fmaxf(fmaxf(s4[0][r], s4[1][r]), fmaxf(s4[2][r], s4[3][r]));
      rm = fmaxf(rm, __shfl_xor(rm, 1));
      rm = fmaxf(rm, __shfl_xor(rm, 2));
      rm = fmaxf(rm, __shfl_xor(rm, 4));
      rm = fmaxf(rm, __shfl_xor(rm, 8));
      const float mnew = fmaxf(m_run[r], rm);
      const float corr = __expf(m_run[r] - mnew);
      m_run[r] = mnew;
      const float p0 = __expf(s4[0][r] - mnew);
      const float p1 = __expf(s4[1][r] - mnew);
      const float p2 = __expf(s4[2][r] - mnew);
      const float p3 = __expf(s4[3][r] - mnew);
      float rs = (p0 + p1) + (p2 + p3);
      rs += __shfl_xor(rs, 1);
      rs += __shfl_xor(rs, 2);
      rs += __shfl_xor(rs, 4);
      rs += __shfl_xor(rs, 8);
      l_run[r] = l_run[r] * corr + rs;
      O[0][r] *= corr; O[1][r] *= corr; O[2][r] *= corr; O[3][r] *= corr;
      const int qrow = g * 4 + r;
      Pl[wave][qrow][ 0 + c] = f2bf(p0);
      Pl[wave][qrow][16 + c] = f2bf(p1);
      Pl[wave][qrow][32 + c] = f2bf(p2);
      Pl[wave][qrow][48 + c] = f2bf(p3);
    }

    // ---- O += P V : A=P from LDS (transposed to A-layout), B=V^T rows ----
    #pragma unroll
    for (int kk = 0; kk < 2; kk++) {
      bf16x8 pa = *reinterpret_cast<const bf16x8*>(&Pl[wave][c][kk * 32 + g * 8]);
      #pragma unroll
      for (int dt = 0; dt < 4; dt++) {
        const u16* vp = vbase + (size_t)(dt * 16 + c) * 2048 + ks0 + kk * 32 + g * 8;
        bf16x8 vb = *reinterpret_cast<const bf16x8*>(vp);
        O[dt] = __builtin_amdgcn_mfma_f32_16x16x32_bf16(pa, vb, O[dt], 0, 0, 0);
      }
    }
  }

  // ---- epilogue: O/l -> ao bf16 [m = s*2+b][p = h*64+d] ----
  #pragma unroll
  for (int r = 0; r < 4; r++) {
    const float inv = 1.0f / l_run[r];
    const int q = q0 + g * 4 + r;
    const size_t m = (size_t)q * 2 + b_;
    #pragma unroll
    for (int dt = 0; dt < 4; dt++) {
      ao[m * 1024 + h * 64 + dt * 16 + c] = f2bf(O[dt][r] * inv);
    }
  }
}

// ---------------- launch ----------------
extern "C" void kernel_launch(void* const* d_in, const int* in_sizes, int n_in,
                              void* d_out, int out_size, void* d_ws, size_t ws_size,
                              hipStream_t stream) {
  const float* src   = (const float*)d_in[0];
  const float* w_in  = (const float*)d_in[1];
  const float* b_in  = (const float*)d_in[2];
  const float* w_out = (const float*)d_in[3];
  const float* b_out = (const float*)d_in[4];
  float* out = (float*)d_out;

  char* ws = (char*)d_ws;
  u16* srcb = (u16*)(ws);                         //  8 MB  src bf16 [4096][1024]
  u16* wib  = (u16*)(ws + ((size_t)8  << 20));    //  6 MB  W_in bf16 [3072][1024]
  u16* wob  = (u16*)(ws + ((size_t)14 << 20));    //  2 MB  W_out bf16 [1024][1024]
  u16* qw   = (u16*)(ws + ((size_t)16 << 20));    //  8 MB  q bf16 [32][2048][64]
  u16* kw   = (u16*)(ws + ((size_t)24 << 20));    //  8 MB  k bf16 [32][2048][64]
  u16* vt   = (u16*)(ws + ((size_t)32 << 20));    //  8 MB  v^T bf16 [32][64][2048]
  u16* ao   = (u16*)(ws + ((size_t)40 << 20));    //  8 MB  attn out bf16 [4096][1024]

  cvt_f32_bf16<<<4096, 256, 0, stream>>>(src,   srcb, 4096 * 1024 / 4);
  cvt_f32_bf16<<<3072, 256, 0, stream>>>(w_in,  wib,  3072 * 1024 / 4);
  cvt_f32_bf16<<<1024, 256, 0, stream>>>(w_out, wob,  1024 * 1024 / 4);

  qkv_gemm<<<dim3(48, 32), 256, 0, stream>>>(srcb, wib, b_in, qw, kw, vt);
  attn_fwd<<<dim3(32, 32), 256, 0, stream>>>(qw, kw, vt, ao);
  out_gemm<<<dim3(16, 32), 256, 0, stream>>>(ao, wob, b_out, out);
}

// Round 3
// 427.505 us; speedup vs baseline: 2.0611x; 1.0011x over previous
//
#include <hip/hip_runtime.h>

// Problem constants
#define S_LEN 2048
#define B_SZ  2
#define F_DIM 1024
#define H_N   16
#define D_DIM 64
#define P_DIM 1024           // H*D
#define M_ROWS 4096          // S*B
#define NBH   32             // B*H

typedef __bf16 bf16x8 __attribute__((ext_vector_type(8)));
typedef float  f32x4  __attribute__((ext_vector_type(4)));
typedef unsigned short u16;
typedef unsigned short u16x8 __attribute__((ext_vector_type(8)));
typedef unsigned short u16x4 __attribute__((ext_vector_type(4)));

__device__ __forceinline__ float bf2f(u16 u) {
  union { unsigned int i; float f; } x;
  x.i = ((unsigned int)u) << 16;
  return x.f;
}
__device__ __forceinline__ u16 f2bf(float f) {
  union { float f; unsigned int i; } x;
  x.f = f;
  unsigned int u = x.i;
  u += 0x7fffu + ((u >> 16) & 1u);   // round-to-nearest-even
  return (u16)(u >> 16);
}

// ---------------- f32 -> bf16 convert (vectorized) ----------------
__global__ __launch_bounds__(256) void cvt_f32_bf16(const float* __restrict__ in,
                                                    u16* __restrict__ out, int n4) {
  int i = blockIdx.x * 256 + threadIdx.x;
  if (i >= n4) return;
  f32x4 v = *reinterpret_cast<const f32x4*>(in + (size_t)i * 4);
  u16x4 o;
  o[0] = f2bf(v[0]); o[1] = f2bf(v[1]); o[2] = f2bf(v[2]); o[3] = f2bf(v[3]);
  *reinterpret_cast<u16x4*>(out + (size_t)i * 4) = o;
}

// ---------------- QKV projection GEMM ----------------
// C[m][p] = sum_f A[m][f] * W[p][f] + bias[p];  A: [4096][1024] bf16, W: [3072][1024] bf16
// Epilogue: scale q by 0.125; scatter to
//   qw [n][s][d]  (scaled q)
//   kw [n][s][d]  (k, row-major — MFMA B-frag wants K rows)
//   vt [n][d][s]  (v transposed — MFMA B-frag for PV wants V^T rows)
__global__ __launch_bounds__(256) void qkv_gemm(const u16* __restrict__ A,
                                                const u16* __restrict__ W,
                                                const float* __restrict__ bias,
                                                u16* __restrict__ qw,
                                                u16* __restrict__ kw,
                                                u16* __restrict__ vt) {
  const int lane = threadIdx.x & 63;
  const int wave = threadIdx.x >> 6;
  const int bm = blockIdx.y * 128;
  const int bn = blockIdx.x * 64;
  const int fr = lane & 15;            // fragment row (m or n within 16)
  const int koff = (lane >> 4) * 8;    // k offset within 32-step

  const u16* Ap0 = A + (size_t)(bm + wave * 32 + fr) * 1024;
  const u16* Ap1 = Ap0 + 16 * 1024;
  const u16* Wp  = W + (size_t)(bn + fr) * 1024;

  f32x4 acc[2][4];
  #pragma unroll
  for (int ai = 0; ai < 2; ai++)
    #pragma unroll
    for (int nt = 0; nt < 4; nt++) {
      f32x4 z = {0.f, 0.f, 0.f, 0.f};
      acc[ai][nt] = z;
    }

  for (int k0 = 0; k0 < 1024; k0 += 32) {
    const int k = k0 + koff;
    bf16x8 a0 = *reinterpret_cast<const bf16x8*>(Ap0 + k);
    bf16x8 a1 = *reinterpret_cast<const bf16x8*>(Ap1 + k);
    #pragma unroll
    for (int nt = 0; nt < 4; nt++) {
      bf16x8 b = *reinterpret_cast<const bf16x8*>(Wp + (size_t)nt * 16 * 1024 + k);
      acc[0][nt] = __builtin_amdgcn_mfma_f32_16x16x32_bf16(a0, b, acc[0][nt], 0, 0, 0);
      acc[1][nt] = __builtin_amdgcn_mfma_f32_16x16x32_bf16(a1, b, acc[1][nt], 0, 0, 0);
    }
  }

  // C/D layout: col = lane&15, row = (lane>>4)*4 + reg   [verified mapping]
  #pragma unroll
  for (int ai = 0; ai < 2; ai++) {
    #pragma unroll
    for (int nt = 0; nt < 4; nt++) {
      const int p = bn + nt * 16 + (lane & 15);
      const float bv = bias[p];
      const int which = p >> 10;          // 0=q 1=k 2=v
      const int pp = p & 1023;
      const int h = pp >> 6, d = pp & 63;
      const float scale = (which == 0) ? 0.125f : 1.0f;
      #pragma unroll
      for (int r = 0; r < 4; r++) {
        const int m = bm + wave * 32 + ai * 16 + (lane >> 4) * 4 + r;
        const int s = m >> 1, b_ = m & 1;
        const int n = b_ * 16 + h;
        const float v = (acc[ai][nt][r] + bv) * scale;
        const u16 hv = f2bf(v);
        if (which == 0)      qw[((size_t)n * 2048 + s) * 64 + d] = hv;
        else if (which == 1) kw[((size_t)n * 2048 + s) * 64 + d] = hv;
        else                 vt[((size_t)n * 64 + d) * 2048 + s] = hv;
      }
    }
  }
}

// ---------------- Output projection GEMM ----------------
// out[m][f] = sum_p A[m][p] * W[f][p] + bias[f];  fp32 output
__global__ __launch_bounds__(256) void out_gemm(const u16* __restrict__ A,
                                                const u16* __restrict__ W,
                                                const float* __restrict__ bias,
                                                float* __restrict__ out) {
  const int lane = threadIdx.x & 63;
  const int wave = threadIdx.x >> 6;
  const int bm = blockIdx.y * 128;
  const int bn = blockIdx.x * 64;
  const int fr = lane & 15;
  const int koff = (lane >> 4) * 8;

  const u16* Ap0 = A + (size_t)(bm + wave * 32 + fr) * 1024;
  const u16* Ap1 = Ap0 + 16 * 1024;
  const u16* Wp  = W + (size_t)(bn + fr) * 1024;

  f32x4 acc[2][4];
  #pragma unroll
  for (int ai = 0; ai < 2; ai++)
    #pragma unroll
    for (int nt = 0; nt < 4; nt++) {
      f32x4 z = {0.f, 0.f, 0.f, 0.f};
      acc[ai][nt] = z;
    }

  for (int k0 = 0; k0 < 1024; k0 += 32) {
    const int k = k0 + koff;
    bf16x8 a0 = *reinterpret_cast<const bf16x8*>(Ap0 + k);
    bf16x8 a1 = *reinterpret_cast<const bf16x8*>(Ap1 + k);
    #pragma unroll
    for (int nt = 0; nt < 4; nt++) {
      bf16x8 b = *reinterpret_cast<const bf16x8*>(Wp + (size_t)nt * 16 * 1024 + k);
      acc[0][nt] = __builtin_amdgcn_mfma_f32_16x16x32_bf16(a0, b, acc[0][nt], 0, 0, 0);
      acc[1][nt] = __builtin_amdgcn_mfma_f32_16x16x32_bf16(a1, b, acc[1][nt], 0, 0, 0);
    }
  }

  #pragma unroll
  for (int ai = 0; ai < 2; ai++) {
    #pragma unroll
    for (int nt = 0; nt < 4; nt++) {
      const int f = bn + nt * 16 + (lane & 15);
      const float bv = bias[f];
      #pragma unroll
      for (int r = 0; r < 4; r++) {
        const int m = bm + wave * 32 + ai * 16 + (lane >> 4) * 4 + r;
        out[(size_t)m * 1024 + f] = acc[ai][nt][r] + bv;
      }
    }
  }
}

// ---------------- Flash attention, bf16 MFMA ----------------
// grid: (32 q-tiles, 32 head-batches), 256 threads = 4 waves.
// Each wave owns 16 q-rows; iterates 32 KV tiles of 64 keys.
// QK^T: A=Q rows (regs), B=K rows (global, L2-resident). S in C-layout.
// Softmax: in-lane over 4 key-subtiles + __shfl_xor over 16 key-lanes.
// P: C-layout -> A-layout via per-wave LDS [16][72] bf16 (padded; no barriers).
// PV: A=P (LDS), B=V^T rows (global).
__global__ __launch_bounds__(256) void attn_fwd(const u16* __restrict__ qw,
                                                const u16* __restrict__ kw,
                                                const u16* __restrict__ vt,
                                                u16* __restrict__ ao) {
  __shared__ u16 Pl[4][16][72];   // per-wave P buffer, +8 pad => conflict-even b128 reads

  const int tid = threadIdx.x;
  const int wave = tid >> 6;
  const int lane = tid & 63;
  const int c = lane & 15;        // frag row/col index
  const int g = lane >> 4;        // k-group within frag
  const int n = blockIdx.y;       // head-batch: n = b*16 + h
  const int qs0 = blockIdx.x * 64;
  const int b_ = n >> 4, h = n & 15;
  const int q0 = qs0 + wave * 16;

  // Q A-frags (held in registers for all 32 KV tiles); q pre-scaled by 1/8
  const u16* qp = qw + ((size_t)n * 2048 + q0 + c) * 64 + g * 8;
  const bf16x8 qa0 = *reinterpret_cast<const bf16x8*>(qp);
  const bf16x8 qa1 = *reinterpret_cast<const bf16x8*>(qp + 32);

  const u16* kbase = kw + (size_t)n * 2048 * 64;   // [s][d]
  const u16* vbase = vt + (size_t)n * 64 * 2048;   // [d][s]

  f32x4 O[4];                     // [dt], rows r=0..3 in regs
  float m_run[4], l_run[4];
  #pragma unroll
  for (int i = 0; i < 4; i++) {
    f32x4 z = {0.f, 0.f, 0.f, 0.f};
    O[i] = z;
    m_run[i] = -1e30f;
    l_run[i] = 0.f;
  }

  for (int kt = 0; kt < 32; kt++) {
    const int ks0 = kt * 64;

    // ---- S = Q K^T (16 q x 64 keys): 4 key-subtiles x 2 k-steps ----
    f32x4 s4[4];
    #pragma unroll
    for (int st = 0; st < 4; st++) { f32x4 z = {0.f,0.f,0.f,0.f}; s4[st] = z; }
    #pragma unroll
    for (int st = 0; st < 4; st++) {
      const u16* kp = kbase + (size_t)(ks0 + st * 16 + c) * 64 + g * 8;
      bf16x8 kb0 = *reinterpret_cast<const bf16x8*>(kp);
      bf16x8 kb1 = *reinterpret_cast<const bf16x8*>(kp + 32);
      s4[st] = __builtin_amdgcn_mfma_f32_16x16x32_bf16(qa0, kb0, s4[st], 0, 0, 0);
      s4[st] = __builtin_amdgcn_mfma_f32_16x16x32_bf16(qa1, kb1, s4[st], 0, 0, 0);
    }

    // ---- online softmax; rows q_local = g*4 + r ----
    #pragma unroll
    for (int r = 0; r < 4; r++) {
      float rm = fmaxf(fmaxf(s4[0][r], s4[1][r]), fmaxf(s4[2][r], s4[3][r]));
      rm = fmaxf(rm, __shfl_xor(rm, 1));
      rm = fmaxf(rm, __shfl_xor(rm, 2));
      rm = fmaxf(rm, __shfl_xor(rm, 4));
      rm = fmaxf(rm, __shfl_xor(rm, 8));
      const float mnew = fmaxf(m_run[r], rm);
      const float corr = __expf(m_run[r] - mnew);
      m_run[r] = mnew;
      const float p0 = __expf(s4[0][r] - mnew);
      const float p1 = __expf(s4[1][r] - mnew);
      const float p2 = __expf(s4[2][r] - mnew);
      const float p3 = __expf(s4[3][r] - mnew);
      float rs = (p0 + p1) + (p2 + p3);
      rs += __shfl_xor(rs, 1);
      rs += __shfl_xor(rs, 2);
      rs += __shfl_xor(rs, 4);
      rs += __shfl_xor(rs, 8);
      l_run[r] = l_run[r] * corr + rs;
      O[0][r] *= corr; O[1][r] *= corr; O[2][r] *= corr; O[3][r] *= corr;
      const int qrow = g * 4 + r;
      Pl[wave][qrow][ 0 + c] = f2bf(p0);
      Pl[wave][qrow][16 + c] = f2bf(p1);
      Pl[wave][qrow][32 + c] = f2bf(p2);
      Pl[wave][qrow][48 + c] = f2bf(p3);
    }

    // ---- O += P V : A=P from LDS (transposed to A-layout), B=V^T rows ----
    #pragma unroll
    for (int kk = 0; kk < 2; kk++) {
      bf16x8 pa = *reinterpret_cast<const bf16x8*>(&Pl[wave][c][kk * 32 + g * 8]);
      #pragma unroll
      for (int dt = 0; dt < 4; dt++) {
        const u16* vp = vbase + (size_t)(dt * 16 + c) * 2048 + ks0 + kk * 32 + g * 8;
        bf16x8 vb = *reinterpret_cast<const bf16x8*>(vp);
        O[dt] = __builtin_amdgcn_mfma_f32_16x16x32_bf16(pa, vb, O[dt], 0, 0, 0);
      }
    }
  }

  // ---- epilogue: O/l -> ao bf16 [m = s*2+b][p = h*64+d] ----
  #pragma unroll
  for (int r = 0; r < 4; r++) {
    const float inv = 1.0f / l_run[r];
    const int q = q0 + g * 4 + r;
    const size_t m = (size_t)q * 2 + b_;
    #pragma unroll
    for (int dt = 0; dt < 4; dt++) {
      ao[m * 1024 + h * 64 + dt * 16 + c] = f2bf(O[dt][r] * inv);
    }
  }
}

// ---------------- launch ----------------
extern "C" void kernel_launch(void* const* d_in, const int* in_sizes, int n_in,
                              void* d_out, int out_size, void* d_ws, size_t ws_size,
                              hipStream_t stream) {
  const float* src   = (const float*)d_in[0];
  const float* w_in  = (const float*)d_in[1];
  const float* b_in  = (const float*)d_in[2];
  const float* w_out = (const float*)d_in[3];
  const float* b_out = (const float*)d_in[4];
  float* out = (float*)d_out;

  char* ws = (char*)d_ws;
  u16* srcb = (u16*)(ws);                         //  8 MB  src bf16 [4096][1024]
  u16* wib  = (u16*)(ws + ((size_t)8  << 20));    //  6 MB  W_in bf16 [3072][1024]
  u16* wob  = (u16*)(ws + ((size_t)14 << 20));    //  2 MB  W_out bf16 [1024][1024]
  u16* qw   = (u16*)(ws + ((size_t)16 << 20));    //  8 MB  q bf16 [32][2048][64]
  u16* kw   = (u16*)(ws + ((size_t)24 << 20));    //  8 MB  k bf16 [32][2048][64]
  u16* vt   = (u16*)(ws + ((size_t)32 << 20));    //  8 MB  v^T bf16 [32][64][2048]
  u16* ao   = (u16*)(ws + ((size_t)40 << 20));    //  8 MB  attn out bf16 [4096][1024]

  cvt_f32_bf16<<<4096, 256, 0, stream>>>(src,   srcb, 4096 * 1024 / 4);
  cvt_f32_bf16<<<3072, 256, 0, stream>>>(w_in,  wib,  3072 * 1024 / 4);
  cvt_f32_bf16<<<1024, 256, 0, stream>>>(w_out, wob,  1024 * 1024 / 4);

  qkv_gemm<<<dim3(48, 32), 256, 0, stream>>>(srcb, wib, b_in, qw, kw, vt);
  attn_fwd<<<dim3(32, 32), 256, 0, stream>>>(qw, kw, vt, ao);
  out_gemm<<<dim3(16, 32), 256, 0, stream>>>(ao, wob, b_out, out);
}